// Round 5
// baseline (353.157 us; speedup 1.0000x reference)
//
#include <hip/hip_runtime.h>

// Problem geometry (fixed by the reference).
#define BATCH 64
#define IMH 512
#define IMW 512
#define NCH 3
#define IMSZ (IMH * IMW * NCH)   // 786432 floats per image
#define NPIX (IMH * IMW)         // 262144 pixels
#define GROUPS 4                 // batch groups (parallelism)
#define BPG (BATCH / GROUPS)     // 16 batches handled per thread

// ---------------------------------------------------------------------------
// Single kernel: each thread owns one output pixel for a group of 16 batches.
// The projective mapping is batch-invariant, so all coordinate math, edge
// handling and weights are computed ONCE and reused 16x.
//
// Tap trick: the 4 bilinear taps form two contiguous 6-float runs
// (pixel pair [xb, xb+1] in rows y0c and y1c). Out-of-range taps have zero
// weight, so we always load the clamped in-bounds pair and REMAP the x-edge
// weights onto the two loaded pixels; loaded garbage is multiplied by 0.
// ---------------------------------------------------------------------------
__global__ __launch_bounds__(256) void warp_kernel(const float* __restrict__ img,
                                                   const float* __restrict__ Mp,
                                                   float* __restrict__ out) {
    const int bid = blockIdx.x;
    const int g = bid & (GROUPS - 1);
    const int pix = ((bid >> 2) << 8) | threadIdx.x;   // 0 .. NPIX-1
    const int x = pix & (IMW - 1);
    const int y = pix >> 9;

    // --- 3x3 inverse of M (uniform across all threads; double for accuracy).
    double a = Mp[0], b = Mp[1], c = Mp[2];
    double d = Mp[3], e = Mp[4], f = Mp[5];
    double gg = Mp[6], h = Mp[7], i = Mp[8];
    double A  =  (e * i - f * h);
    double Bq = -(d * i - f * gg);
    double Cq =  (d * h - e * gg);
    double invdet = 1.0 / (a * A + b * Bq + c * Cq);
    const float m0 = (float)(A * invdet);
    const float m1 = (float)(-(b * i - c * h) * invdet);
    const float m2 = (float)((b * f - c * e) * invdet);
    const float m3 = (float)(Bq * invdet);
    const float m4 = (float)((a * i - c * gg) * invdet);
    const float m5 = (float)(-(a * f - c * d) * invdet);
    const float m6 = (float)(Cq * invdet);
    const float m7 = (float)(-(a * h - b * gg) * invdet);
    const float m8 = (float)((a * e - b * d) * invdet);

    // --- Projective map for this pixel (once).
    const float fx = (float)x, fy = (float)y;
    const float s0 = fmaf(m0, fx, fmaf(m1, fy, m2));
    const float s1 = fmaf(m3, fx, fmaf(m4, fy, m5));
    const float s2 = fmaf(m6, fx, fmaf(m7, fy, m8));
    const float r2 = __builtin_amdgcn_rcpf(s2);   // s2 in [~1.0, 1.15], well conditioned
    const float u = s0 * r2;
    const float v = s1 * r2;

    const float x0f = floorf(u), y0f = floorf(v);
    const float wx = u - x0f,   wy = v - y0f;
    const int x0 = (int)x0f, y0 = (int)y0f;
    const int x1 = x0 + 1,   y1 = y0 + 1;

    // Clamped load coordinates (always in-bounds).
    const int xb  = min(max(x0, 0), IMW - 2);       // load pixels xb, xb+1
    const int y0c = min(max(y0, 0), IMH - 1);
    const int y1c = min(max(y1, 0), IMH - 1);

    // Validity-masked x weights, remapped onto the loaded pixel pair.
    const float w0x = (x0 >= 0 && x0 < IMW) ? (1.0f - wx) : 0.0f;
    const float w1x = (x1 >= 0 && x1 < IMW) ? wx : 0.0f;
    const float b0 = (x0 == xb     ? w0x : 0.0f) + (x1 == xb     ? w1x : 0.0f);
    const float b1 = (x0 == xb + 1 ? w0x : 0.0f) + (x1 == xb + 1 ? w1x : 0.0f);
    // Validity-masked y weights.
    const float wy0 = (y0 >= 0 && y0 < IMH) ? (1.0f - wy) : 0.0f;
    const float wy1 = (y1 >= 0 && y1 < IMH) ? wy : 0.0f;

    const float c00 = wy0 * b0, c01 = wy0 * b1;    // row y0c: loaded px0, px1
    const float c10 = wy1 * b0, c11 = wy1 * b1;    // row y1c: loaded px0, px1

    const size_t off0 = ((size_t)y0c * IMW + xb) * NCH;
    const size_t off1 = ((size_t)y1c * IMW + xb) * NCH;
    const float* p0 = img + (size_t)g * BPG * IMSZ + off0;
    const float* p1 = img + (size_t)g * BPG * IMSZ + off1;
    float* o = out + ((size_t)g * BPG * NPIX + pix) * NCH;

    // --- Batch loop: 16 images, identical mapping. 24B contiguous per row.
    #pragma unroll 4
    for (int t = 0; t < BPG; ++t) {
        float r0[6], r1[6];
        __builtin_memcpy(r0, p0, 24);   // pixels (y0c, xb) and (y0c, xb+1)
        __builtin_memcpy(r1, p1, 24);   // pixels (y1c, xb) and (y1c, xb+1)

        const float o0 = c00 * r0[0] + c01 * r0[3] + c10 * r1[0] + c11 * r1[3];
        const float o1 = c00 * r0[1] + c01 * r0[4] + c10 * r1[1] + c11 * r1[4];
        const float o2 = c00 * r0[2] + c01 * r0[5] + c10 * r1[2] + c11 * r1[5];

        __builtin_nontemporal_store(o0, o + 0);
        __builtin_nontemporal_store(o1, o + 1);
        __builtin_nontemporal_store(o2, o + 2);

        p0 += IMSZ;
        p1 += IMSZ;
        o  += (size_t)NPIX * NCH;
    }
}

extern "C" void kernel_launch(void* const* d_in, const int* in_sizes, int n_in,
                              void* d_out, int out_size, void* d_ws, size_t ws_size,
                              hipStream_t stream) {
    const float* imgs = (const float*)d_in[0];
    const float* M = (const float*)d_in[1];
    float* out = (float*)d_out;

    const int blocks = (NPIX / 256) * GROUPS;  // 1024 * 4 = 4096
    warp_kernel<<<blocks, 256, 0, stream>>>(imgs, M, out);
}

// Round 6
// 349.129 us; speedup vs baseline: 1.0115x; 1.0115x over previous
//
#include <hip/hip_runtime.h>

// Problem geometry (fixed by the reference).
#define BATCH 64
#define IMH 512
#define IMW 512
#define NCH 3
#define IMSZ (IMH * IMW * NCH)   // 786432 floats per image
#define NPIX (IMH * IMW)         // 262144 pixels
#define GROUPS 16                // batch groups (parallelism)
#define BPG (BATCH / GROUPS)     // 4 batches handled per thread

// ---------------------------------------------------------------------------
// Each thread owns one output pixel for a group of BPG batches. The projective
// mapping is batch-invariant, so coordinate math / edge handling / weights are
// computed once and reused.
//
// Tap trick: the 4 bilinear taps form two contiguous 6-float runs (pixel pair
// [xb, xb+1] in rows y0c, y1c). Out-of-range taps get zero weight, so we load
// the clamped in-bounds pair and remap x-edge weights onto the loaded pixels.
//
// Latency fix (round 5 profile: 129us @ 2.35 TB/s, VALUBusy 8% -> latency
// bound): ALL batch loads are issued before any compute (fully unrolled
// load phase), and GROUPS=16 quadruples wave count vs round 5.
// ---------------------------------------------------------------------------
__global__ __launch_bounds__(256) void warp_kernel(const float* __restrict__ img,
                                                   const float* __restrict__ Mp,
                                                   float* __restrict__ out) {
    const int bid = blockIdx.x;
    const int g = bid & (GROUPS - 1);
    const int pix = ((bid >> 4) << 8) | threadIdx.x;   // 0 .. NPIX-1
    const int x = pix & (IMW - 1);
    const int y = pix >> 9;

    // --- 3x3 inverse of M (uniform across all threads; double for accuracy).
    double a = Mp[0], b = Mp[1], c = Mp[2];
    double d = Mp[3], e = Mp[4], f = Mp[5];
    double gg = Mp[6], h = Mp[7], i = Mp[8];
    double A  =  (e * i - f * h);
    double Bq = -(d * i - f * gg);
    double Cq =  (d * h - e * gg);
    double invdet = 1.0 / (a * A + b * Bq + c * Cq);
    const float m0 = (float)(A * invdet);
    const float m1 = (float)(-(b * i - c * h) * invdet);
    const float m2 = (float)((b * f - c * e) * invdet);
    const float m3 = (float)(Bq * invdet);
    const float m4 = (float)((a * i - c * gg) * invdet);
    const float m5 = (float)(-(a * f - c * d) * invdet);
    const float m6 = (float)(Cq * invdet);
    const float m7 = (float)(-(a * h - b * gg) * invdet);
    const float m8 = (float)((a * e - b * d) * invdet);

    // --- Projective map for this pixel (once).
    const float fx = (float)x, fy = (float)y;
    const float s0 = fmaf(m0, fx, fmaf(m1, fy, m2));
    const float s1 = fmaf(m3, fx, fmaf(m4, fy, m5));
    const float s2 = fmaf(m6, fx, fmaf(m7, fy, m8));
    const float r2 = __builtin_amdgcn_rcpf(s2);   // s2 in [~1.0, 1.15], well conditioned
    const float u = s0 * r2;
    const float v = s1 * r2;

    const float x0f = floorf(u), y0f = floorf(v);
    const float wx = u - x0f,   wy = v - y0f;
    const int x0 = (int)x0f, y0 = (int)y0f;
    const int x1 = x0 + 1,   y1 = y0 + 1;

    // Clamped load coordinates (always in-bounds).
    const int xb  = min(max(x0, 0), IMW - 2);       // load pixels xb, xb+1
    const int y0c = min(max(y0, 0), IMH - 1);
    const int y1c = min(max(y1, 0), IMH - 1);

    // Validity-masked x weights, remapped onto the loaded pixel pair.
    const float w0x = (x0 >= 0 && x0 < IMW) ? (1.0f - wx) : 0.0f;
    const float w1x = (x1 >= 0 && x1 < IMW) ? wx : 0.0f;
    const float b0 = (x0 == xb     ? w0x : 0.0f) + (x1 == xb     ? w1x : 0.0f);
    const float b1 = (x0 == xb + 1 ? w0x : 0.0f) + (x1 == xb + 1 ? w1x : 0.0f);
    // Validity-masked y weights.
    const float wy0 = (y0 >= 0 && y0 < IMH) ? (1.0f - wy) : 0.0f;
    const float wy1 = (y1 >= 0 && y1 < IMH) ? wy : 0.0f;

    const float c00 = wy0 * b0, c01 = wy0 * b1;    // row y0c: loaded px0, px1
    const float c10 = wy1 * b0, c11 = wy1 * b1;    // row y1c: loaded px0, px1

    const size_t off0 = ((size_t)y0c * IMW + xb) * NCH;
    const size_t off1 = ((size_t)y1c * IMW + xb) * NCH;
    const float* p0 = img + (size_t)g * BPG * IMSZ + off0;
    const float* p1 = img + (size_t)g * BPG * IMSZ + off1;
    float* o = out + ((size_t)g * BPG * NPIX + pix) * NCH;

    // --- Phase 1: issue ALL loads (2 rows x BPG batches, 24B each) before
    // any compute, so every load is in flight concurrently.
    float r0[BPG][6], r1[BPG][6];
    #pragma unroll
    for (int t = 0; t < BPG; ++t) {
        __builtin_memcpy(r0[t], p0 + (size_t)t * IMSZ, 24);
        __builtin_memcpy(r1[t], p1 + (size_t)t * IMSZ, 24);
    }

    // --- Phase 2: blend and store (static indices only; stays in registers).
    #pragma unroll
    for (int t = 0; t < BPG; ++t) {
        const float o0 = c00 * r0[t][0] + c01 * r0[t][3] + c10 * r1[t][0] + c11 * r1[t][3];
        const float o1 = c00 * r0[t][1] + c01 * r0[t][4] + c10 * r1[t][1] + c11 * r1[t][4];
        const float o2 = c00 * r0[t][2] + c01 * r0[t][5] + c10 * r1[t][2] + c11 * r1[t][5];
        float* ot = o + (size_t)t * (NPIX * NCH);
        __builtin_nontemporal_store(o0, ot + 0);
        __builtin_nontemporal_store(o1, ot + 1);
        __builtin_nontemporal_store(o2, ot + 2);
    }
}

extern "C" void kernel_launch(void* const* d_in, const int* in_sizes, int n_in,
                              void* d_out, int out_size, void* d_ws, size_t ws_size,
                              hipStream_t stream) {
    const float* imgs = (const float*)d_in[0];
    const float* M = (const float*)d_in[1];
    float* out = (float*)d_out;

    const int blocks = (NPIX / 256) * GROUPS;  // 1024 * 16 = 16384
    warp_kernel<<<blocks, 256, 0, stream>>>(imgs, M, out);
}